// Round 9
// baseline (163.758 us; speedup 1.0000x reference)
//
#include <hip/hip_runtime.h>

typedef __attribute__((ext_vector_type(8))) short short8;
typedef __attribute__((ext_vector_type(4))) float f32x4;
typedef __attribute__((ext_vector_type(4))) unsigned int u32x4;

#define NTOK 4096
#define DIM  256
#define P_STRIDE 72        // P row stride elems (144 B); chunk kc at pos = kc ^ (2*((r>>3)&1))
#define TILE_ELEMS 32768   // ushort elems per 64KB tile image (Ks 16384 | Kt 16384)

__device__ __forceinline__ unsigned pack2bf(float a, float b) {
  unsigned ua = __builtin_bit_cast(unsigned, a) + 0x8000u;
  unsigned ub = __builtin_bit_cast(unsigned, b) + 0x8000u;
  return __builtin_amdgcn_perm(ub, ua, 0x07060302u); // low=bf16(a), high=bf16(b)
}

// ---- prologue v2: single X read, LDS-staged transpose (verified R3) ------
__global__ __launch_bounds__(256, 4)
void prep_kernel(const float* __restrict__ X, unsigned short* __restrict__ Img) {
  __shared__ __align__(16) unsigned short rowbf[8 * 256];  // 4 KB bf16 stage
  const int b    = blockIdx.x & 3;
  const int sub  = blockIdx.x >> 2;   // 0..511
  const int t    = sub >> 3;
  const int part = sub & 7;
  const int tid  = threadIdx.x;
  const float* src = X + ((size_t)b * NTOK + t * 64 + part * 8) * DIM;
  unsigned short* dst = Img + ((size_t)(b * 64 + t)) * TILE_ELEMS;
  {
    const int r = tid >> 5;   // row within the 8-row slab
    const int c = tid & 31;   // 16B chunk within the row
    const float* s = src + r * DIM + c * 8;
    f32x4 f0 = *(const f32x4*)s;
    f32x4 f1 = *(const f32x4*)(s + 4);
    union { unsigned u[4]; u32x4 v; } p;
    p.u[0] = pack2bf(f0[0], f0[1]);
    p.u[1] = pack2bf(f0[2], f0[3]);
    p.u[2] = pack2bf(f1[0], f1[1]);
    p.u[3] = pack2bf(f1[2], f1[3]);
    const int gr = part * 8 + r;
    *(u32x4*)(dst + gr * 256 + ((c ^ (gr & 7)) << 3)) = p.v;
    *(u32x4*)(&rowbf[r * 256 + c * 8]) = p.v;
  }
  __syncthreads();
  {
    const int d = tid;        // one column per thread
    union { unsigned short s[8]; u32x4 v; } p;
    #pragma unroll
    for (int i = 0; i < 8; ++i) p.s[i] = rowbf[i * 256 + d];
    *(u32x4*)(dst + 16384 + part * 2048 + d * 8) = p.v;
  }
}

// ---- flash-attention v9: specialized waves, K AND V all-register ---------
// Pipe-sum model (R4/R5/R8: MFMA+VALU+LDS sum to wall): shrink the sum.
// In the specialized design each Ks byte had ZERO LDS reuse (DMA-write once,
// ds_read once by one wave) -> K staging deleted. QK waves load K fragments
// straight from the L2-hot Ks image (same scattered-16B pattern V uses),
// single-buffered: the ~300cyc L2 latency staggers QK vs PV so the PV wave
// owns the MFMA pipe meanwhile. LDS now only carries P (19.5 KB).
// T5 setprio around both MFMA clusters (role diversity exists).
#define FA_STEP(T, VLD, VUS)                                                   \
  {                                                                            \
    const int t_ = (T);                                                        \
    __syncthreads();  /* publishes P(t-1); drains V(t-1) reg loads */          \
    const int buf_ = t_ & 1;                                                   \
    if (!isQK) {                                                               \
      {                                                                        \
        const unsigned short* vt = vtg + (size_t)t_ * TILE_ELEMS;              \
        _Pragma("unroll")                                                      \
        for (int ks = 0; ks < 2; ++ks)                                         \
          _Pragma("unroll")                                                    \
          for (int dt = 0; dt < 4; ++dt)                                       \
            u[(VLD) + ks * 4 + dt] = __builtin_bit_cast(f32x4,                 \
                *(const short8*)(vt + (ks * 4 + quad) * 2048 + dt * 128));     \
      }                                                                        \
      if (t_ > 0) {                                                            \
        const unsigned short* prd = pb[buf_ ^ 1];                              \
        __builtin_amdgcn_s_setprio(1);                                         \
        _Pragma("unroll")                                                      \
        for (int ks = 0; ks < 2; ++ks) {                                       \
          const int pos = (ks * 4 + quad) ^ ((ln >> 3) << 1);                  \
          _Pragma("unroll")                                                    \
          for (int s = 0; s < 4; ++s) {                                        \
            short8 ap = *(const short8*)(                                      \
                &prd[(s * 16 + ln) * P_STRIDE + (pos << 3)]);                  \
            _Pragma("unroll")                                                  \
            for (int dt = 0; dt < 4; ++dt)                                     \
              u[s * 4 + dt] = __builtin_amdgcn_mfma_f32_16x16x32_bf16(         \
                  ap, __builtin_bit_cast(short8, u[(VUS) + ks * 4 + dt]),      \
                  u[s * 4 + dt], 0, 0, 0);                                     \
          }                                                                    \
        }                                                                      \
        __builtin_amdgcn_s_setprio(0);                                         \
      }                                                                        \
    } else {                                                                   \
      /* K(t) fragments straight from global Ks image (L2-hot) */              \
      const unsigned short* kR =                                               \
          imgb + (size_t)t_ * TILE_ELEMS + (role * 16 + ln) * 256;             \
      short8 bk[8];                                                            \
      _Pragma("unroll")                                                        \
      for (int ds = 0; ds < 8; ++ds)                                           \
        bk[ds] = *(const short8*)(kR + (((ds * 4 + quad) ^ swz) << 3));        \
      f32x4 sf[4];                                                             \
      _Pragma("unroll")                                                        \
      for (int s = 0; s < 4; ++s) sf[s] = (f32x4)(0.0f);                       \
      __builtin_amdgcn_s_setprio(1);                                           \
      _Pragma("unroll")                                                        \
      for (int ds = 0; ds < 8; ++ds)                                           \
        _Pragma("unroll")                                                      \
        for (int s = 0; s < 4; ++s)                                            \
          sf[s] = __builtin_amdgcn_mfma_f32_16x16x32_bf16(                     \
              __builtin_bit_cast(short8, u[s * 8 + ds]), bk[ds], sf[s],        \
              0, 0, 0);                                                        \
      __builtin_amdgcn_s_setprio(0);                                           \
      unsigned short* pw = pb[buf_];                                           \
      _Pragma("unroll")                                                        \
      for (int s = 0; s < 4; ++s) {                                            \
        unsigned pd[4];                                                        \
        _Pragma("unroll")                                                      \
        for (int j = 0; j < 4; ++j) {                                          \
          float p0 = __builtin_amdgcn_exp2f(sf[s][j] * c2);                    \
          lrow[s][j] += p0;                                                    \
          unsigned q0 = __builtin_bit_cast(unsigned, p0);                      \
          unsigned n0 = (unsigned)__builtin_amdgcn_mov_dpp((int)q0, 0xB1,      \
                                                           0xF, 0xF, true);   \
          pd[j] = pack2bf(p0, __builtin_bit_cast(float, n0));                  \
        }                                                                      \
        if ((ln & 1) == 0) {                                                   \
          _Pragma("unroll")                                                    \
          for (int j = 0; j < 4; ++j)                                          \
            *(unsigned*)(&pw[(s * 16 + quad * 4 + j) * P_STRIDE +              \
                             pwPos + pwCol]) = pd[j];                          \
        }                                                                      \
      }                                                                        \
    }                                                                          \
  }

__global__ __launch_bounds__(512, 1)
void fa_kernel(const unsigned short* __restrict__ Img, float* __restrict__ Out) {
  __shared__ __align__(16) unsigned short pb[2][64 * P_STRIDE]; // 18 KB P dbuf
  __shared__ float lbuf[64][4];                                 // 1 KB

  const int tid  = threadIdx.x;
  const int b    = blockIdx.x & 3;
  const int qblk = blockIdx.x >> 2;
  const int wave = tid >> 6;
  const int lane = tid & 63;
  const int ln   = lane & 15;
  const int quad = lane >> 4;
  const int swz  = ln & 7;
  const bool isQK = wave < 4;
  const int  role = wave & 3;  // QK: key-16 group; PV: d-quarter

  const unsigned short* imgb = Img + (size_t)b * 64 * TILE_ELEMS;

  const float c2 = 0.0901684400f;  // log2(e)/sqrt(256)

  // P write constants (QK waves): kc = role*2 + (ln>>3); pos = kc ^ (2*(quad>>1))
  const int pwPos = ((role * 2 + (ln >> 3)) ^ ((quad >> 1) << 1)) << 3;
  const int pwCol = ln & 7;

  // PV: V-frag base in Kt image
  const unsigned short* vtg = imgb + 16384 + (size_t)(role * 64 + ln) * 8;

  float lrow[4][4] = {{0,0,0,0},{0,0,0,0},{0,0,0,0},{0,0,0,0}};

  // Register overlay: QK waves -> aQ[s][ds] = u[s*8+ds];
  //                   PV waves -> o[s][dt] = u[s*4+dt], V[set][ks][dt] = u[16+set*8+ks*4+dt]
  f32x4 u[32];
  if (isQK) {
    #pragma unroll
    for (int s = 0; s < 4; ++s) {
      const unsigned short* qrow =
          imgb + (size_t)qblk * TILE_ELEMS + (s * 16 + ln) * 256;
      #pragma unroll
      for (int ds = 0; ds < 8; ++ds)
        u[s * 8 + ds] = __builtin_bit_cast(f32x4,
            *(const short8*)(qrow + (((ds * 4 + quad) ^ swz) << 3)));
    }
  } else {
    #pragma unroll
    for (int i = 0; i < 16; ++i) u[i] = (f32x4)(0.0f);
  }

  FA_STEP(0, 16, 24);
  #pragma unroll 1
  for (int tt = 1; tt < 63; tt += 2) {
    FA_STEP(tt, 24, 16);
    FA_STEP(tt + 1, 16, 24);
  }
  FA_STEP(63, 24, 16);

  __syncthreads();  // drains V(63) reg loads; P(63) resident in pb[1]

  if (isQK) {
    // merge l over the 16 key-lanes of this role
    #pragma unroll
    for (int off = 1; off < 16; off <<= 1)
      #pragma unroll
      for (int s = 0; s < 4; ++s)
        #pragma unroll
        for (int j = 0; j < 4; ++j)
          lrow[s][j] += __shfl_xor(lrow[s][j], off, 64);
    if (ln == 0) {
      #pragma unroll
      for (int s = 0; s < 4; ++s)
        #pragma unroll
        for (int j = 0; j < 4; ++j)
          lbuf[s * 16 + quad * 4 + j][role] = lrow[s][j];
    }
  } else {
    // final PV(63): P from pb[1], V set = 24
    const unsigned short* prd = pb[1];
    #pragma unroll
    for (int ks = 0; ks < 2; ++ks) {
      const int pos = (ks * 4 + quad) ^ ((ln >> 3) << 1);
      #pragma unroll
      for (int s = 0; s < 4; ++s) {
        short8 ap = *(const short8*)(&prd[(s * 16 + ln) * P_STRIDE + (pos << 3)]);
        #pragma unroll
        for (int dt = 0; dt < 4; ++dt)
          u[s * 4 + dt] = __builtin_amdgcn_mfma_f32_16x16x32_bf16(
              ap, __builtin_bit_cast(short8, u[24 + ks * 4 + dt]),
              u[s * 4 + dt], 0, 0, 0);
      }
    }
  }
  __syncthreads();  // lbuf ready

  if (!isQK) {
    float* outB = Out + (size_t)(b * NTOK + qblk * 64) * DIM + role * 64;
    #pragma unroll
    for (int s = 0; s < 4; ++s) {
      #pragma unroll
      for (int j = 0; j < 4; ++j) {
        const int row = s * 16 + quad * 4 + j;
        f32x4 lv = *(const f32x4*)lbuf[row];
        const float rl = 1.0f / (lv[0] + lv[1] + lv[2] + lv[3]);
        #pragma unroll
        for (int dt = 0; dt < 4; ++dt)
          outB[(size_t)row * DIM + dt * 16 + ln] = u[s * 4 + dt][j] * rl;
      }
    }
  }
}

extern "C" void kernel_launch(void* const* d_in, const int* in_sizes, int n_in,
                              void* d_out, int out_size, void* d_ws, size_t ws_size,
                              hipStream_t stream) {
  const float* X = (const float*)d_in[0];       // x: fp32 [4,4096,256]
  float* Out = (float*)d_out;                   // fp32 [4,4096,256]
  unsigned short* Img = (unsigned short*)d_ws;  // 16 MB bf16 tile images
  (void)in_sizes; (void)n_in; (void)out_size; (void)ws_size;
  hipLaunchKernelGGL(prep_kernel, dim3(2048), dim3(256), 0, stream, X, Img);
  hipLaunchKernelGGL(fa_kernel, dim3(256), dim3(512), 0, stream, Img, Out);
}

// Round 10
// 144.084 us; speedup vs baseline: 1.1365x; 1.1365x over previous
//
#include <hip/hip_runtime.h>

typedef __attribute__((ext_vector_type(8))) short short8;
typedef __attribute__((ext_vector_type(4))) float f32x4;
typedef __attribute__((ext_vector_type(4))) unsigned int u32x4;

#define NTOK 4096
#define DIM  256
#define P_STRIDE 72        // P row stride elems (144 B); chunk kc at pos = kc ^ (2*((r>>3)&1))
#define TILE_ELEMS 32768   // ushort elems per 64KB tile image (Ks 16384 | Kt 16384)

__device__ __forceinline__ unsigned pack2bf(float a, float b) {
  unsigned ua = __builtin_bit_cast(unsigned, a) + 0x8000u;
  unsigned ub = __builtin_bit_cast(unsigned, b) + 0x8000u;
  return __builtin_amdgcn_perm(ub, ua, 0x07060302u); // low=bf16(a), high=bf16(b)
}

// ---- prologue v2: single X read, LDS-staged transpose (verified R3) ------
__global__ __launch_bounds__(256, 4)
void prep_kernel(const float* __restrict__ X, unsigned short* __restrict__ Img) {
  __shared__ __align__(16) unsigned short rowbf[8 * 256];  // 4 KB bf16 stage
  const int b    = blockIdx.x & 3;
  const int sub  = blockIdx.x >> 2;   // 0..511
  const int t    = sub >> 3;
  const int part = sub & 7;
  const int tid  = threadIdx.x;
  const float* src = X + ((size_t)b * NTOK + t * 64 + part * 8) * DIM;
  unsigned short* dst = Img + ((size_t)(b * 64 + t)) * TILE_ELEMS;
  {
    const int r = tid >> 5;   // row within the 8-row slab
    const int c = tid & 31;   // 16B chunk within the row
    const float* s = src + r * DIM + c * 8;
    f32x4 f0 = *(const f32x4*)s;
    f32x4 f1 = *(const f32x4*)(s + 4);
    union { unsigned u[4]; u32x4 v; } p;
    p.u[0] = pack2bf(f0[0], f0[1]);
    p.u[1] = pack2bf(f0[2], f0[3]);
    p.u[2] = pack2bf(f1[0], f1[1]);
    p.u[3] = pack2bf(f1[2], f1[3]);
    const int gr = part * 8 + r;
    *(u32x4*)(dst + gr * 256 + ((c ^ (gr & 7)) << 3)) = p.v;
    *(u32x4*)(&rowbf[r * 256 + c * 8]) = p.v;
  }
  __syncthreads();
  {
    const int d = tid;        // one column per thread
    union { unsigned short s[8]; u32x4 v; } p;
    #pragma unroll
    for (int i = 0; i < 8; ++i) p.s[i] = rowbf[i * 256 + d];
    *(u32x4*)(dst + 16384 + part * 2048 + d * 8) = p.v;
  }
}

// ---- flash-attention v10: specialized waves + 2-deep deferred softmax ----
// R9 falsified the pipe-sum model (3 data plans, same wall): the binder is
// the per-iter serial chain {K-lat -> MFMA -> exp/pack VALU -> store}.
// T15 fix: defer tile t's softmax to iter t+1, placed BETWEEN K-load issue
// and the MFMA cluster -> VALU fills the K L2-latency window and co-issues
// with the MFMA pipe. P pipeline deepens to 2 (PV(t) eats P(t-2)); pb[2]
// still works: write pb[(t-1)&1], read pb[t&1], disjoint. V sets shift to
// (t-2) with consume-before-reload (loads get 2 iters to land).
#define PV_TAIL(PRD, SB)                                                       \
  {                                                                            \
    const unsigned short* prd = (PRD);                                         \
    _Pragma("unroll")                                                          \
    for (int ks = 0; ks < 2; ++ks) {                                           \
      const int pos = (ks * 4 + quad) ^ ((ln >> 3) << 1);                      \
      _Pragma("unroll")                                                        \
      for (int s = 0; s < 4; ++s) {                                            \
        short8 ap = *(const short8*)(&prd[(s * 16 + ln) * P_STRIDE +           \
                                          (pos << 3)]);                        \
        _Pragma("unroll")                                                      \
        for (int dt = 0; dt < 4; ++dt)                                         \
          u[s * 4 + dt] = __builtin_amdgcn_mfma_f32_16x16x32_bf16(             \
              ap, __builtin_bit_cast(short8, u[(SB) + ks * 4 + dt]),           \
              u[s * 4 + dt], 0, 0, 0);                                         \
      }                                                                        \
    }                                                                          \
  }

#define FA_STEP(T, SETB)                                                       \
  {                                                                            \
    const int t_ = (T);                                                        \
    __syncthreads();  /* publishes P(t-2) in pb[t&1]; orders pb reuse */       \
    if (!isQK) {                                                               \
      if (t_ > 1) {                                                            \
        __builtin_amdgcn_s_setprio(1);                                         \
        PV_TAIL(pb[t_ & 1], SETB);   /* P(t-2) x V(t-2) */                     \
        __builtin_amdgcn_s_setprio(0);                                         \
      }                                                                        \
      { /* reload set with V(t); consumed at t+2 -> 2 iters to land */         \
        const unsigned short* vt = vtg + (size_t)t_ * TILE_ELEMS;              \
        _Pragma("unroll")                                                      \
        for (int ks = 0; ks < 2; ++ks)                                         \
          _Pragma("unroll")                                                    \
          for (int dt = 0; dt < 4; ++dt)                                       \
            u[(SETB) + ks * 4 + dt] = __builtin_bit_cast(f32x4,                \
                *(const short8*)(vt + (ks * 4 + quad) * 2048 + dt * 128));     \
      }                                                                        \
    } else {                                                                   \
      /* 1) issue K(t) loads (L2-hot) */                                       \
      const unsigned short* kR =                                               \
          imgb + (size_t)t_ * TILE_ELEMS + (role * 16 + ln) * 256;             \
      short8 bk[8];                                                            \
      _Pragma("unroll")                                                        \
      for (int ds = 0; ds < 8; ++ds)                                           \
        bk[ds] = *(const short8*)(kR + (((ds * 4 + quad) ^ swz) << 3));        \
      /* 2) deferred softmax of tile t-1 (VALU; overlaps K latency+MFMA) */    \
      if (t_ > 0) expstore((t_ & 1) ^ 1);                                      \
      /* 3) QK MFMA into sfo (first ds starts from zero) */                    \
      __builtin_amdgcn_s_setprio(1);                                           \
      _Pragma("unroll")                                                        \
      for (int s = 0; s < 4; ++s)                                              \
        sfo[s] = __builtin_amdgcn_mfma_f32_16x16x32_bf16(                      \
            __builtin_bit_cast(short8, u[s * 8]), bk[0], (f32x4)(0.0f),        \
            0, 0, 0);                                                          \
      _Pragma("unroll")                                                        \
      for (int ds = 1; ds < 8; ++ds)                                           \
        _Pragma("unroll")                                                      \
        for (int s = 0; s < 4; ++s)                                            \
          sfo[s] = __builtin_amdgcn_mfma_f32_16x16x32_bf16(                    \
              __builtin_bit_cast(short8, u[s * 8 + ds]), bk[ds], sfo[s],       \
              0, 0, 0);                                                        \
      __builtin_amdgcn_s_setprio(0);                                           \
    }                                                                          \
  }

__global__ __launch_bounds__(512, 1)
void fa_kernel(const unsigned short* __restrict__ Img, float* __restrict__ Out) {
  __shared__ __align__(16) unsigned short pb[2][64 * P_STRIDE]; // 18 KB P dbuf
  __shared__ float lbuf[64][4];                                 // 1 KB

  const int tid  = threadIdx.x;
  const int b    = blockIdx.x & 3;
  const int qblk = blockIdx.x >> 2;
  const int wave = tid >> 6;
  const int lane = tid & 63;
  const int ln   = lane & 15;
  const int quad = lane >> 4;
  const int swz  = ln & 7;
  const bool isQK = wave < 4;
  const int  role = wave & 3;  // QK: key-16 group; PV: d-quarter

  const unsigned short* imgb = Img + (size_t)b * 64 * TILE_ELEMS;

  const float c2 = 0.0901684400f;  // log2(e)/sqrt(256)

  // P write constants (QK waves): kc = role*2 + (ln>>3); pos = kc ^ (2*(quad>>1))
  const int pwPos = ((role * 2 + (ln >> 3)) ^ ((quad >> 1) << 1)) << 3;
  const int pwCol = ln & 7;

  // PV: V-frag base in Kt image
  const unsigned short* vtg = imgb + 16384 + (size_t)(role * 64 + ln) * 8;

  float lrow[4][4] = {{0,0,0,0},{0,0,0,0},{0,0,0,0},{0,0,0,0}};
  f32x4 sfo[4];  // QK: scores of the PREVIOUS tile (deferred softmax)

  // Register overlay: QK waves -> aQ[s][ds] = u[s*8+ds];
  //                   PV waves -> o[s][dt] = u[s*4+dt], V sets at u[16+set*8+..]
  f32x4 u[32];
  if (isQK) {
    #pragma unroll
    for (int s = 0; s < 4; ++s) {
      const unsigned short* qrow =
          imgb + (size_t)qblk * TILE_ELEMS + (s * 16 + ln) * 256;
      #pragma unroll
      for (int ds = 0; ds < 8; ++ds)
        u[s * 8 + ds] = __builtin_bit_cast(f32x4,
            *(const short8*)(qrow + (((ds * 4 + quad) ^ swz) << 3)));
    }
  } else {
    #pragma unroll
    for (int i = 0; i < 16; ++i) u[i] = (f32x4)(0.0f);
  }

  // deferred-softmax of sfo -> pb[pwbuf] (QK waves only)
  auto expstore = [&](int pwbuf) __attribute__((always_inline)) {
    unsigned short* pw = pb[pwbuf];
    #pragma unroll
    for (int s = 0; s < 4; ++s) {
      unsigned pd[4];
      #pragma unroll
      for (int j = 0; j < 4; ++j) {
        float p0 = __builtin_amdgcn_exp2f(sfo[s][j] * c2);
        lrow[s][j] += p0;
        unsigned q0 = __builtin_bit_cast(unsigned, p0);
        unsigned n0 = (unsigned)__builtin_amdgcn_mov_dpp((int)q0, 0xB1,
                                                         0xF, 0xF, true);
        pd[j] = pack2bf(p0, __builtin_bit_cast(float, n0));
      }
      if ((ln & 1) == 0) {
        #pragma unroll
        for (int j = 0; j < 4; ++j)
          *(unsigned*)(&pw[(s * 16 + quad * 4 + j) * P_STRIDE +
                           pwPos + pwCol]) = pd[j];
      }
    }
  };

  #pragma unroll 1
  for (int tt = 0; tt < 64; tt += 2) {
    FA_STEP(tt, 16);       // even t: V set base 16
    FA_STEP(tt + 1, 24);   // odd  t: V set base 24
  }
  // state: P(62) in pb[0] (stored at t=63); sfo = sf(63);
  //        V(62) in set 16, V(63) in set 24.

  __syncthreads();  // publishes P(62)
  if (isQK) {
    expstore(1);    // P(63) -> pb[1]
  } else {
    PV_TAIL(pb[0], 16);  // P(62) x V(62)
  }
  __syncthreads();  // publishes P(63)

  if (isQK) {
    // merge l over the 16 key-lanes of this role
    #pragma unroll
    for (int off = 1; off < 16; off <<= 1)
      #pragma unroll
      for (int s = 0; s < 4; ++s)
        #pragma unroll
        for (int j = 0; j < 4; ++j)
          lrow[s][j] += __shfl_xor(lrow[s][j], off, 64);
    if (ln == 0) {
      #pragma unroll
      for (int s = 0; s < 4; ++s)
        #pragma unroll
        for (int j = 0; j < 4; ++j)
          lbuf[s * 16 + quad * 4 + j][role] = lrow[s][j];
    }
  } else {
    PV_TAIL(pb[1], 24);  // P(63) x V(63)
  }
  __syncthreads();  // lbuf ready

  if (!isQK) {
    float* outB = Out + (size_t)(b * NTOK + qblk * 64) * DIM + role * 64;
    #pragma unroll
    for (int s = 0; s < 4; ++s) {
      #pragma unroll
      for (int j = 0; j < 4; ++j) {
        const int row = s * 16 + quad * 4 + j;
        f32x4 lv = *(const f32x4*)lbuf[row];
        const float rl = 1.0f / (lv[0] + lv[1] + lv[2] + lv[3]);
        #pragma unroll
        for (int dt = 0; dt < 4; ++dt)
          outB[(size_t)row * DIM + dt * 16 + ln] = u[s * 4 + dt][j] * rl;
      }
    }
  }
}

extern "C" void kernel_launch(void* const* d_in, const int* in_sizes, int n_in,
                              void* d_out, int out_size, void* d_ws, size_t ws_size,
                              hipStream_t stream) {
  const float* X = (const float*)d_in[0];       // x: fp32 [4,4096,256]
  float* Out = (float*)d_out;                   // fp32 [4,4096,256]
  unsigned short* Img = (unsigned short*)d_ws;  // 16 MB bf16 tile images
  (void)in_sizes; (void)n_in; (void)out_size; (void)ws_size;
  hipLaunchKernelGGL(prep_kernel, dim3(2048), dim3(256), 0, stream, X, Img);
  hipLaunchKernelGGL(fa_kernel, dim3(256), dim3(512), 0, stream, Img, Out);
}